// Round 5
// baseline (158.232 us; speedup 1.0000x reference)
//
#include <hip/hip_runtime.h>
#include <hip/hip_bf16.h>

// EfficientSelfAttention (PVT-style), B=8, N=16384 (128x128), C=64, 1 head, SR=8.
// Round 5: attn occupancy (V from L2, 32KB LDS, 512-thread blocks), VALU trim
// (hw bf16 cvt, deferred inv, single-term proj), lnkv 256-thread blocks.
//
// ws layout (bytes):
//   wbp      512KB  conv weights bf16, permuted for coalesced A-frag loads
//   conv_out 512KB  f32 conv accumulator (bias-init by prep, atomics by conv)
//   kbuf     256KB  K bf16 [b][256][64]
//   vp       256KB  V bf16 permuted [b][ks][g][ch][i]
//   qwb      8KB    q_w * scale, bf16
//   pwp      8KB    proj_w bf16, permuted
//   qb_s     256B   q_b * scale, f32

typedef __attribute__((ext_vector_type(8))) short bf16x8;
typedef __attribute__((ext_vector_type(4))) float f32x4;

__device__ __forceinline__ unsigned short f2bf(float f) {
    union { __hip_bfloat16 h; unsigned short u; } cv;
    cv.h = __hip_bfloat16(f);
    return cv.u;
}
union U8 { uint4 u; bf16x8 v; };
__device__ __forceinline__ bf16x8 pack8(float e0,float e1,float e2,float e3,
                                        float e4,float e5,float e6,float e7){
    U8 r;
    r.u.x = (unsigned)f2bf(e0) | ((unsigned)f2bf(e1)<<16);
    r.u.y = (unsigned)f2bf(e2) | ((unsigned)f2bf(e3)<<16);
    r.u.z = (unsigned)f2bf(e4) | ((unsigned)f2bf(e5)<<16);
    r.u.w = (unsigned)f2bf(e6) | ((unsigned)f2bf(e7)<<16);
    return r.v;
}
__device__ __forceinline__ bf16x8 ldg8(const unsigned short* p){
    U8 r; r.u = *(const uint4*)p; return r.v;
}

// ---------------- kernel 0: weight permutes + conv_out bias init -------------
__global__ __launch_bounds__(256) void prep_kernel(
    const float* __restrict__ sr_w, const float* __restrict__ sr_b,
    const float* __restrict__ q_w, const float* __restrict__ q_b,
    const float* __restrict__ proj_w,
    unsigned short* __restrict__ wbp, float* __restrict__ conv_out,
    unsigned short* __restrict__ qwb, unsigned short* __restrict__ pwp,
    float* __restrict__ qb_s)
{
    int tid = blockIdx.x * 256 + threadIdx.x;   // 0..262143
    {   // wbp[((((w*4+kc)*32+ks)*4+g)*16+n)*8+i] = bf16(W[16w+n][kc*1024+ks*32+8g+i])
        int i = tid & 7, n = (tid>>3)&15, g = (tid>>7)&3, ks = (tid>>9)&31,
            kc = (tid>>14)&3, w = tid>>16;
        int co = 16*w + n;
        int k  = kc*1024 + ks*32 + 8*g + i;
        int kh = k >> 9, kw = (k>>6)&7, cin = k & 63;
        wbp[tid] = f2bf(sr_w[co*4096 + cin*64 + kh*8 + kw]);
    }
    if (tid < 131072) conv_out[tid] = sr_b[tid & 63];
    if (tid < 4096)   qwb[tid] = f2bf(q_w[tid] * 0.125f);
    if (tid < 4096) { // pwp[((co*2+s3)*4+g)*8+i] = pw[co][16*(2s3+(i>>2))+4g+(i&3)]
        int i = tid & 7, g = (tid>>3)&3, s3 = (tid>>5)&1, co = tid>>6;
        int ch = 32*s3 + 16*(i>>2) + 4*g + (i&3);
        pwp[tid] = f2bf(proj_w[co*64 + ch]);
    }
    if (tid < 64) qb_s[tid] = q_b[tid] * 0.125f;
}

// ---------------- kernel 1: 8x8/8 conv as bf16 MFMA GEMM (k-split, atomics) --
// grid: b(8) x oh(16) x kc(4) = 512 blocks, 256 threads (4 waves, 1 co-tile each)
__global__ __launch_bounds__(256) void conv_kernel(
    const float* __restrict__ x, const unsigned short* __restrict__ wbp,
    float* __restrict__ conv_out)
{
    __shared__ char xsm[32768];   // 2 rows x 128 w x 64 cin bf16, XOR-swizzled by ow
    int bid = blockIdx.x;
    int kc = bid & 3, oh = (bid>>2) & 15, b = bid >> 6;
    int t = threadIdx.x;

    const float* slab = x + ((size_t)(b*128 + oh*8 + kc*2)) * 128 * 64;
    #pragma unroll
    for (int c2 = 0; c2 < 8; ++c2) {
        int eo = (c2*256 + t) * 8;
        float4 v0 = *(const float4*)(slab + eo);
        float4 v1 = *(const float4*)(slab + eo + 4);
        int byte = eo * 2;
        int dst = byte ^ (((byte >> 10) & 7) << 4);   // swizzle by ow row
        U8 tmp; tmp.v = pack8(v0.x,v0.y,v0.z,v0.w,v1.x,v1.y,v1.z,v1.w);
        *(uint4*)(xsm + dst) = tmp.u;
    }
    __syncthreads();

    int w = t >> 6, lane = t & 63, g = lane >> 4, n = lane & 15;
    f32x4 acc = {0.f, 0.f, 0.f, 0.f};
    const unsigned short* wslice = wbp + (size_t)((w*4 + kc) * 32) * 512; // *4*16*8
    int swz = (n & 7) << 4;
    #pragma unroll
    for (int ks = 0; ks < 32; ++ks) {
        bf16x8 A = ldg8(wslice + ((ks*4 + g)*16 + n) * 8);
        int byte = (ks >> 4) * 16384 + n * 1024 + ((ks & 15) * 32 + 8*g) * 2;
        U8 Bx; Bx.u = *(const uint4*)(xsm + (byte ^ swz));
        acc = __builtin_amdgcn_mfma_f32_16x16x32_bf16(A, Bx.v, acc, 0, 0, 0);
    }
    int pos = b*256 + oh*16 + n;
    int co  = 16*w + 4*g;
    #pragma unroll
    for (int r = 0; r < 4; ++r)
        atomicAdd(&conv_out[pos*64 + co + r], acc[r]);
}

// ---------------- kernel 2: LayerNorm + kv proj -> kbuf bf16, vp bf16 --------
// grid 512 x 256 threads; each wave handles one (b, m)
__global__ __launch_bounds__(256) void lnkv_kernel(
    const float* __restrict__ conv_out,
    const float* __restrict__ ln_g, const float* __restrict__ ln_b,
    const float* __restrict__ kv_w, const float* __restrict__ kv_b,
    unsigned short* __restrict__ kbuf, unsigned short* __restrict__ vp)
{
    int wv = threadIdx.x >> 6, c = threadIdx.x & 63;
    int gblk = blockIdx.x * 4 + wv;   // b*256 + m
    int b = gblk >> 8, m = gblk & 255;
    float val = conv_out[gblk*64 + c];
    float s = val, s2 = val*val;
    #pragma unroll
    for (int o = 32; o >= 1; o >>= 1) {
        s  += __shfl_xor(s,  o, 64);
        s2 += __shfl_xor(s2, o, 64);
    }
    float mean = s * (1.f/64.f);
    float var  = s2 * (1.f/64.f) - mean*mean;
    float y = (val - mean) * rsqrtf(var + 1e-5f) * ln_g[c] + ln_b[c];
    __shared__ float ys[4][64];
    ys[wv][c] = y;
    __syncthreads();
    #pragma unroll
    for (int h = 0; h < 2; ++h) {
        int oc = c + h*64;
        float acc = kv_b[oc];
        const float* wr = kv_w + oc*64;
        #pragma unroll
        for (int j = 0; j < 64; j += 4) {
            float4 w4 = *(const float4*)(wr + j);
            acc += ys[wv][j]*w4.x + ys[wv][j+1]*w4.y + ys[wv][j+2]*w4.z + ys[wv][j+3]*w4.w;
        }
        if (h == 0) {
            kbuf[(b*256 + m)*64 + c] = f2bf(acc);
        } else {    // vp[b][((ks*4+g)*64+ch)*8 + (m&3) + 4*hi], m = 16(2ks+hi)+4g+r
            int ks = m >> 5, hi = (m >> 4) & 1, g2 = (m >> 2) & 3, r = m & 3;
            vp[(size_t)b*16384 + ((ks*4 + g2)*64 + c)*8 + r + 4*hi] = f2bf(acc);
        }
    }
}

// ---------------- kernel 3: fused q-proj/QK^T/softmax/PV/out-proj, all MFMA --
// grid: b(8) x 128 row-tiles = 1024 blocks; 8 waves x 16 q-rows = 128 rows/block
__global__ __launch_bounds__(512) void attn_kernel(
    const float* __restrict__ x,
    const unsigned short* __restrict__ qwb, const float* __restrict__ qb_s,
    const unsigned short* __restrict__ kbuf, const unsigned short* __restrict__ vp,
    const unsigned short* __restrict__ pwp, const float* __restrict__ proj_b,
    float* __restrict__ out)
{
    __shared__ char Ks[32768];   // K bf16 [256][64], XOR-swizzled rows
    int bid = blockIdx.x;
    int b = bid >> 7, rt = bid & 127;
    int t = threadIdx.x;
    {
        const char* kb = (const char*)(kbuf + (size_t)b*16384);
        #pragma unroll
        for (int c = 0; c < 4; ++c) {
            int off = (c*512 + t) * 16;
            int dst = off ^ (((off >> 7) & 7) << 4);
            *(uint4*)(Ks + dst) = *(const uint4*)(kb + off);
        }
    }
    __syncthreads();

    int w = t >> 6, lane = t & 63, g = lane >> 4, n = lane & 15;
    int qrow = rt*128 + w*16 + n;
    const float* xr = x + ((size_t)b*16384 + qrow) * 64;
    const char* vpb = (const char*)(vp + (size_t)b*16384);

    // ---- q-proj: qT[co][q] = sum_cin qwb[co][cin] * x[q][cin], +qb_s (scaled)
    f32x4 qacc[4];
    #pragma unroll
    for (int tau = 0; tau < 4; ++tau)
        qacc[tau] = *(const f32x4*)(qb_s + 16*tau + 4*g);
    bf16x8 xq[2];
    #pragma unroll
    for (int s = 0; s < 2; ++s) {
        float4 v0 = *(const float4*)(xr + 32*s + 8*g);
        float4 v1 = *(const float4*)(xr + 32*s + 8*g + 4);
        xq[s] = pack8(v0.x,v0.y,v0.z,v0.w,v1.x,v1.y,v1.z,v1.w);
    }
    #pragma unroll
    for (int tau = 0; tau < 4; ++tau)
        #pragma unroll
        for (int s = 0; s < 2; ++s) {
            bf16x8 A = ldg8(qwb + (16*tau + n)*64 + 32*s + 8*g);
            qacc[tau] = __builtin_amdgcn_mfma_f32_16x16x32_bf16(A, xq[s], qacc[tau], 0,0,0);
        }
    // pack Q^T B-frags: mu(g,i,s2) = 16*(2s2+(i>>2)) + 4g + (i&3) -> reg (tau,r)
    bf16x8 qkB[2];
    #pragma unroll
    for (int s2 = 0; s2 < 2; ++s2)
        qkB[s2] = pack8(qacc[2*s2][0],  qacc[2*s2][1],  qacc[2*s2][2],  qacc[2*s2][3],
                        qacc[2*s2+1][0],qacc[2*s2+1][1],qacc[2*s2+1][2],qacc[2*s2+1][3]);

    // ---- QK^T (swapped): S^T[m][q]; lane owns m = 16*tt + 4g + r for q = n
    float S[16][4];
    #pragma unroll
    for (int tt = 0; tt < 16; ++tt) {
        f32x4 sa = {0.f, 0.f, 0.f, 0.f};
        int m = 16*tt + n;
        int base = m * 128;
        int swz = (m & 7) << 4;
        #pragma unroll
        for (int s2 = 0; s2 < 2; ++s2) {
            int c1 = (32*s2 + 4*g) * 2;
            uint2 d0 = *(const uint2*)(Ks + ((base + c1)      ^ swz));
            uint2 d1 = *(const uint2*)(Ks + ((base + c1 + 32) ^ swz));
            U8 A; A.u = make_uint4(d0.x, d0.y, d1.x, d1.y);
            sa = __builtin_amdgcn_mfma_f32_16x16x32_bf16(A.v, qkB[s2], sa, 0,0,0);
        }
        S[tt][0]=sa[0]; S[tt][1]=sa[1]; S[tt][2]=sa[2]; S[tt][3]=sa[3];
    }

    // ---- softmax over m=256: lane-local tree + shfl_xor over 16,32
    float rm[16];
    #pragma unroll
    for (int tt = 0; tt < 16; ++tt)
        rm[tt] = fmaxf(fmaxf(S[tt][0],S[tt][1]), fmaxf(S[tt][2],S[tt][3]));
    float m8[8];
    #pragma unroll
    for (int j = 0; j < 8; ++j) m8[j] = fmaxf(rm[2*j], rm[2*j+1]);
    float mx = fmaxf(fmaxf(fmaxf(m8[0],m8[1]),fmaxf(m8[2],m8[3])),
                     fmaxf(fmaxf(m8[4],m8[5]),fmaxf(m8[6],m8[7])));
    mx = fmaxf(mx, __shfl_xor(mx, 16, 64));
    mx = fmaxf(mx, __shfl_xor(mx, 32, 64));
    #pragma unroll
    for (int tt = 0; tt < 16; ++tt)
        #pragma unroll
        for (int r = 0; r < 4; ++r)
            S[tt][r] = __expf(S[tt][r] - mx);
    float rs[16];
    #pragma unroll
    for (int tt = 0; tt < 16; ++tt) rs[tt] = (S[tt][0]+S[tt][1]) + (S[tt][2]+S[tt][3]);
    float s8[8];
    #pragma unroll
    for (int j = 0; j < 8; ++j) s8[j] = rs[2*j] + rs[2*j+1];
    float ssum = ((s8[0]+s8[1])+(s8[2]+s8[3])) + ((s8[4]+s8[5])+(s8[6]+s8[7]));
    ssum += __shfl_xor(ssum, 16, 64);
    ssum += __shfl_xor(ssum, 32, 64);
    float inv = 1.f / ssum;   // deferred: applied to oacc after PV

    // ---- PV: out^T[ch][q] = sum_m V^T[ch][m] P^T[m][q]; P lane-local, unnormalized
    f32x4 oacc[4] = {{0,0,0,0},{0,0,0,0},{0,0,0,0},{0,0,0,0}};
    #pragma unroll
    for (int ks = 0; ks < 8; ++ks) {
        bf16x8 Bp = pack8(S[2*ks][0],  S[2*ks][1],  S[2*ks][2],  S[2*ks][3],
                          S[2*ks+1][0],S[2*ks+1][1],S[2*ks+1][2],S[2*ks+1][3]);
        #pragma unroll
        for (int tc = 0; tc < 4; ++tc) {
            U8 A; A.u = *(const uint4*)(vpb + ((ks*4 + g)*64 + 16*tc + n) * 16);
            oacc[tc] = __builtin_amdgcn_mfma_f32_16x16x32_bf16(A.v, Bp, oacc[tc], 0,0,0);
        }
    }

    // ---- out-proj (single bf16 term): final^T[co][q] = pw x (inv*attnout^T) + pb
    bf16x8 Bo[2];
    #pragma unroll
    for (int s3 = 0; s3 < 2; ++s3)
        Bo[s3] = pack8(oacc[2*s3][0]*inv,   oacc[2*s3][1]*inv,
                       oacc[2*s3][2]*inv,   oacc[2*s3][3]*inv,
                       oacc[2*s3+1][0]*inv, oacc[2*s3+1][1]*inv,
                       oacc[2*s3+1][2]*inv, oacc[2*s3+1][3]*inv);
    f32x4 pacc[4];
    #pragma unroll
    for (int tf = 0; tf < 4; ++tf)
        pacc[tf] = *(const f32x4*)(proj_b + 16*tf + 4*g);
    #pragma unroll
    for (int tf = 0; tf < 4; ++tf)
        #pragma unroll
        for (int s3 = 0; s3 < 2; ++s3) {
            bf16x8 Aw = ldg8(pwp + (((16*tf + n)*2 + s3)*4 + g)*8);
            pacc[tf] = __builtin_amdgcn_mfma_f32_16x16x32_bf16(Aw, Bo[s3], pacc[tf], 0,0,0);
        }
    float* orow = out + ((size_t)b*16384 + qrow) * 64;
    #pragma unroll
    for (int tf = 0; tf < 4; ++tf)
        *(float4*)(orow + 16*tf + 4*g) = *(float4*)&pacc[tf];
}

extern "C" void kernel_launch(void* const* d_in, const int* in_sizes, int n_in,
                              void* d_out, int out_size, void* d_ws, size_t ws_size,
                              hipStream_t stream)
{
    const float* x      = (const float*)d_in[0];
    const float* sr_w   = (const float*)d_in[1];
    const float* sr_b   = (const float*)d_in[2];
    const float* ln_g   = (const float*)d_in[3];
    const float* ln_b   = (const float*)d_in[4];
    const float* q_w    = (const float*)d_in[5];
    const float* q_b    = (const float*)d_in[6];
    const float* kv_w   = (const float*)d_in[7];
    const float* kv_b   = (const float*)d_in[8];
    const float* proj_w = (const float*)d_in[9];
    const float* proj_b = (const float*)d_in[10];
    float* out = (float*)d_out;

    char* wsb = (char*)d_ws;
    unsigned short* wbp  = (unsigned short*)(wsb);            // 512KB
    float*          conv = (float*)(wsb + 524288);            // 512KB
    unsigned short* kbuf = (unsigned short*)(wsb + 1048576);  // 256KB
    unsigned short* vp   = (unsigned short*)(wsb + 1310720);  // 256KB
    unsigned short* qwb  = (unsigned short*)(wsb + 1572864);  // 8KB
    unsigned short* pwp  = (unsigned short*)(wsb + 1581056);  // 8KB
    float*          qb_s = (float*)(wsb + 1589248);           // 256B

    hipLaunchKernelGGL(prep_kernel, dim3(1024), dim3(256), 0, stream,
                       sr_w, sr_b, q_w, q_b, proj_w, wbp, conv, qwb, pwp, qb_s);
    hipLaunchKernelGGL(conv_kernel, dim3(512), dim3(256), 0, stream, x, wbp, conv);
    hipLaunchKernelGGL(lnkv_kernel, dim3(512), dim3(256), 0, stream,
                       conv, ln_g, ln_b, kv_w, kv_b, kbuf, vp);
    hipLaunchKernelGGL(attn_kernel, dim3(1024), dim3(512), 0, stream,
                       x, qwb, qb_s, kbuf, vp, pwp, proj_b, out);
}